// Round 3
// baseline (321.044 us; speedup 1.0000x reference)
//
#include <hip/hip_runtime.h>

#define NSTEP 64
#define HDIM 1024
#define BDIM 2048
#define OHH 511

// ---------------------------------------------------------------------------
// Kernel 1: precompute (cos th, sin th, sin phi, cos phi) tables + omega table
// etab[64][512], otab[64][512] (slot 511 = identity), wtab[1024]
// Inputs are f32 (verified round 2: WRITE_SIZE == f32 output size).
// ---------------------------------------------------------------------------
__global__ void coeff_kernel(const float* __restrict__ omega,
                             const float* __restrict__ ETh,
                             const float* __restrict__ OTh,
                             const float* __restrict__ EPh,
                             const float* __restrict__ OPh,
                             float4* __restrict__ etab,
                             float4* __restrict__ otab,
                             float2* __restrict__ wtab)
{
    int idx = blockIdx.x * 256 + threadIdx.x;
    if (idx < NSTEP * 512) {
        float c, s, cp, sp;
        sincosf(ETh[idx], &s, &c);
        sincosf(EPh[idx], &sp, &cp);
        etab[idx] = make_float4(c, s, sp, cp);
    } else if (idx < 2 * NSTEP * 512) {
        int i = idx - NSTEP * 512;
        int l = i >> 9;
        int j = i & 511;
        float4 v;
        if (j < OHH) {
            float c, s, cp, sp;
            sincosf(OTh[l * OHH + j], &s, &c);
            sincosf(OPh[l * OHH + j], &sp, &cp);
            v = make_float4(c, s, sp, cp);
        } else {
            v = make_float4(1.f, 0.f, 1.f, 0.f);  // identity rotation
        }
        otab[i] = v;
    } else if (idx < 2 * NSTEP * 512 + HDIM) {
        int c = idx - 2 * NSTEP * 512;
        float cw, sw;
        sincosf(omega[c], &sw, &cw);
        wtab[c] = make_float2(cw, sw);
    }
}

// ---------------------------------------------------------------------------
// Kernel 2: one wave = ONE row (2048 waves -> 2 waves/SIMD for latency
// hiding); lane owns 16 consecutive columns in registers. Even pairs are
// lane-internal; odd pairs: 7 internal + 2 boundary via shfl with redundant
// boundary-pair compute. Boundary even-pairs (k=0,7) computed first so the
// 4 boundary shuffles issue early and hide ds_bpermute latency.
// ---------------------------------------------------------------------------
__global__ __launch_bounds__(256) void eunn_kernel(
    const float* __restrict__ x_re,
    const float* __restrict__ x_im,
    const float4* __restrict__ etab,
    const float4* __restrict__ otab,
    const float2* __restrict__ wtab,
    float* __restrict__ out)
{
    const int lane = threadIdx.x & 63;
    const int wave = threadIdx.x >> 6;
    const int row = blockIdx.x * 4 + wave;
    const int colbase = lane << 4;
    const int lofs = lane << 3;                 // 8*lane: pair-table offset
    const int lofs0 = (lofs + 511) & 511;       // left-boundary odd pair (lane0 -> identity)

    float xr[16], xi[16];

    // --- load state (f32), 4x float4 per array ---
    {
        const float4* pr = reinterpret_cast<const float4*>(x_re + row * HDIM + colbase);
        const float4* pi = reinterpret_cast<const float4*>(x_im + row * HDIM + colbase);
        #pragma unroll
        for (int q = 0; q < 4; ++q) {
            float4 vr = pr[q];
            float4 vi = pi[q];
            xr[4*q] = vr.x; xr[4*q+1] = vr.y; xr[4*q+2] = vr.z; xr[4*q+3] = vr.w;
            xi[4*q] = vi.x; xi[4*q+1] = vi.y; xi[4*q+2] = vi.z; xi[4*q+3] = vi.w;
        }
    }

    // --- preload even coeffs for step 0 ---
    float4 ec[8];
    {
        const float4* p = etab + lofs;
        #pragma unroll
        for (int k = 0; k < 8; ++k) ec[k] = p[k];
    }

    for (int s = 0; s < NSTEP; ++s) {
        // prefetch odd coeffs for this step (covered by even-layer compute)
        float4 oc0 = otab[s * 512 + lofs0];
        float4 oc[8];
        {
            const float4* p = otab + s * 512 + lofs;   // lane63 k=7 -> identity
            #pragma unroll
            for (int k = 0; k < 8; ++k) oc[k] = p[k];
        }

        // ---- even layer, boundary pairs first (k=0 -> cols 0,1; k=7 -> cols 14,15)
        #pragma unroll
        for (int t = 0; t < 2; ++t) {
            int k = t ? 7 : 0;
            float c = ec[k].x, sn = ec[k].y, sp = ec[k].z, cp = ec[k].w;
            float ar = xr[2*k],   ai = xi[2*k];
            float br = xr[2*k+1], bi = xi[2*k+1];
            float tr = c*ar - sn*br;
            float ti = c*ai - sn*bi;
            xr[2*k]   = sp*tr - cp*ti;
            xi[2*k]   = sp*ti + cp*tr;
            xr[2*k+1] = c*br + sn*ar;
            xi[2*k+1] = c*bi + sn*ai;
        }

        // boundary shuffles on post-even values (issue early, use late)
        float xnr = __shfl_down(xr[0], 1, 64);   // right neighbor's col0
        float xni = __shfl_down(xi[0], 1, 64);
        float xlr = __shfl_up(xr[15], 1, 64);    // left neighbor's col15
        float xli = __shfl_up(xi[15], 1, 64);

        // remaining even pairs k=1..6
        #pragma unroll
        for (int k = 1; k < 7; ++k) {
            float c = ec[k].x, sn = ec[k].y, sp = ec[k].z, cp = ec[k].w;
            float ar = xr[2*k],   ai = xi[2*k];
            float br = xr[2*k+1], bi = xi[2*k+1];
            float tr = c*ar - sn*br;
            float ti = c*ai - sn*bi;
            xr[2*k]   = sp*tr - cp*ti;
            xi[2*k]   = sp*ti + cp*tr;
            xr[2*k+1] = c*br + sn*ar;
            xi[2*k+1] = c*bi + sn*ai;
        }

        // prefetch next step's even coeffs (covered by odd-layer compute)
        if (s + 1 < NSTEP) {
            const float4* p = etab + (s + 1) * 512 + lofs;
            #pragma unroll
            for (int k = 0; k < 8; ++k) ec[k] = p[k];
        }

        // ---- odd layer: internal pairs oc[k-1] -> cols (2k-1, 2k), k=1..7
        #pragma unroll
        for (int k = 1; k < 8; ++k) {
            float c = oc[k-1].x, sn = oc[k-1].y, sp = oc[k-1].z, cp = oc[k-1].w;
            float ar = xr[2*k-1], ai = xi[2*k-1];
            float br = xr[2*k],   bi = xi[2*k];
            float tr = c*ar - sn*br;
            float ti = c*ai - sn*bi;
            xr[2*k-1] = sp*tr - cp*ti;
            xi[2*k-1] = sp*ti + cp*tr;
            xr[2*k]   = c*br + sn*ar;
            xi[2*k]   = c*bi + sn*ai;
        }
        // right boundary pair (our col15 = "a", neighbor col0 = "b"): update col15
        {
            float c = oc[7].x, sn = oc[7].y, sp = oc[7].z, cp = oc[7].w;
            float ar = xr[15], ai = xi[15];
            float tr = c*ar - sn*xnr;
            float ti = c*ai - sn*xni;
            xr[15] = sp*tr - cp*ti;
            xi[15] = sp*ti + cp*tr;
        }
        // left boundary pair (left col15 = "a", our col0 = "b"): update col0
        {
            float c = oc0.x, sn = oc0.y;
            float br = xr[0], bi = xi[0];
            xr[0] = c*br + sn*xlr;
            xi[0] = c*bi + sn*xli;
        }
    }

    // --- omega phase + store (f32) ---
    const float4* wt4 = reinterpret_cast<const float4*>(wtab) + lofs;
    float4* pre = reinterpret_cast<float4*>(out + row * HDIM + colbase);
    float4* pim = reinterpret_cast<float4*>(out + BDIM * HDIM + row * HDIM + colbase);
    #pragma unroll
    for (int h = 0; h < 4; ++h) {
        float4 wa = wt4[2*h];      // (cw,sw) cols 4h, 4h+1
        float4 wb = wt4[2*h + 1];  // (cw,sw) cols 4h+2, 4h+3
        float4 vr, vi;
        vr.x = xr[4*h]   * wa.x - xi[4*h]   * wa.y;
        vi.x = xr[4*h]   * wa.y + xi[4*h]   * wa.x;
        vr.y = xr[4*h+1] * wa.z - xi[4*h+1] * wa.w;
        vi.y = xr[4*h+1] * wa.w + xi[4*h+1] * wa.z;
        vr.z = xr[4*h+2] * wb.x - xi[4*h+2] * wb.y;
        vi.z = xr[4*h+2] * wb.y + xi[4*h+2] * wb.x;
        vr.w = xr[4*h+3] * wb.z - xi[4*h+3] * wb.w;
        vi.w = xr[4*h+3] * wb.w + xi[4*h+3] * wb.z;
        pre[h] = vr;
        pim[h] = vi;
    }
}

extern "C" void kernel_launch(void* const* d_in, const int* in_sizes, int n_in,
                              void* d_out, int out_size, void* d_ws, size_t ws_size,
                              hipStream_t stream)
{
    const float* x_re  = (const float*)d_in[0];
    const float* x_im  = (const float*)d_in[1];
    const float* omega = (const float*)d_in[2];
    const float* eth   = (const float*)d_in[3];
    const float* oth   = (const float*)d_in[4];
    const float* eph   = (const float*)d_in[5];
    const float* oph   = (const float*)d_in[6];

    char* ws = (char*)d_ws;
    float4* etab = (float4*)ws;                             // 512 KB
    float4* otab = (float4*)(ws + NSTEP * 512 * 16);        // 512 KB
    float2* wtab = (float2*)(ws + 2 * NSTEP * 512 * 16);    // 8 KB

    coeff_kernel<<<260, 256, 0, stream>>>(omega, eth, oth, eph, oph, etab, otab, wtab);
    eunn_kernel<<<BDIM / 4, 256, 0, stream>>>(x_re, x_im, etab, otab, wtab, (float*)d_out);
}

// Round 4
// 165.995 us; speedup vs baseline: 1.9341x; 1.9341x over previous
//
#include <hip/hip_runtime.h>

#define NSTEP 64
#define HDIM 1024
#define BDIM 2048
#define OHH 511

// ---------------------------------------------------------------------------
// Kernel 1: precompute transposed coefficient tables.
//   etab[s][k][lane]  (float4 c,s,sp,cp), slot = s*512 + k*64 + lane,
//     holding even pair p = 8*lane + k  (pair p covers cols 2p, 2p+1)
//   otab same for odd pair j = 8*lane + k (covers cols 2j+1, 2j+2);
//     j == 511 -> identity (absorbs both chain ends)
//   wtab[q][lane] float4 = (cw,sw,cw,sw) for cols (16*lane+2q, 16*lane+2q+1)
// Transposed so the eunn kernel's per-lane loads are lane-stride-16B
// coalesced (round 3 showed divergent stride-128B loads are the bottleneck:
// ~64 cyc of L1 port per instruction vs ~4 coalesced).
// ---------------------------------------------------------------------------
__global__ void coeff_kernel(const float* __restrict__ omega,
                             const float* __restrict__ ETh,
                             const float* __restrict__ OTh,
                             const float* __restrict__ EPh,
                             const float* __restrict__ OPh,
                             float4* __restrict__ etab,
                             float4* __restrict__ otab,
                             float2* __restrict__ wtab)
{
    int idx = blockIdx.x * 256 + threadIdx.x;
    if (idx < NSTEP * 512) {
        int p = idx & 511;
        float c, s, cp, sp;
        sincosf(ETh[idx], &s, &c);
        sincosf(EPh[idx], &sp, &cp);
        etab[(idx & ~511) | ((p & 7) << 6) | (p >> 3)] = make_float4(c, s, sp, cp);
    } else if (idx < 2 * NSTEP * 512) {
        int i2 = idx - NSTEP * 512;
        int l = i2 >> 9;
        int j = i2 & 511;
        float4 v;
        if (j < OHH) {
            float c, s, cp, sp;
            sincosf(OTh[l * OHH + j], &s, &c);
            sincosf(OPh[l * OHH + j], &sp, &cp);
            v = make_float4(c, s, sp, cp);
        } else {
            v = make_float4(1.f, 0.f, 1.f, 0.f);  // identity rotation
        }
        otab[(i2 & ~511) | ((j & 7) << 6) | (j >> 3)] = v;
    } else if (idx < 2 * NSTEP * 512 + HDIM) {
        int c = idx - 2 * NSTEP * 512;
        float cw, sw;
        sincosf(omega[c], &sw, &cw);
        int p = c >> 1;
        wtab[(((p & 7) << 6) | (p >> 3)) * 2 + (c & 1)] = make_float2(cw, sw);
    }
}

// ---------------------------------------------------------------------------
// Kernel 2: one wave = 2 rows (1024 waves); lane owns 16 consecutive columns
// of both rows in registers. Even pairs lane-internal; odd pairs: 7 internal
// + 2 boundary via shfl with redundant boundary-pair compute. All coefficient
// loads are coalesced via the transposed tables.
// ---------------------------------------------------------------------------
__global__ __launch_bounds__(256) void eunn_kernel(
    const float* __restrict__ x_re,
    const float* __restrict__ x_im,
    const float4* __restrict__ etab,
    const float4* __restrict__ otab,
    const float4* __restrict__ wtab,
    float* __restrict__ out)
{
    const int lane = threadIdx.x & 63;
    const int wave = threadIdx.x >> 6;
    const int row0 = blockIdx.x * 8 + wave * 2;
    const int colbase = lane << 4;
    const int lanem1 = (lane + 63) & 63;   // oc0 slot: k=7 row of lane-1 (lane0 -> identity)

    float xr[2][16], xi[2][16];

    // --- load state (f32), coalesced float4 ---
    #pragma unroll
    for (int r = 0; r < 2; ++r) {
        const float4* pr = reinterpret_cast<const float4*>(x_re + (row0 + r) * HDIM + colbase);
        const float4* pi = reinterpret_cast<const float4*>(x_im + (row0 + r) * HDIM + colbase);
        #pragma unroll
        for (int q = 0; q < 4; ++q) {
            float4 vr = pr[q];
            float4 vi = pi[q];
            xr[r][4*q] = vr.x; xr[r][4*q+1] = vr.y; xr[r][4*q+2] = vr.z; xr[r][4*q+3] = vr.w;
            xi[r][4*q] = vi.x; xi[r][4*q+1] = vi.y; xi[r][4*q+2] = vi.z; xi[r][4*q+3] = vi.w;
        }
    }

    // --- preload even coeffs for step 0 (coalesced: lane-stride 16 B) ---
    float4 ec[8];
    {
        const float4* p = etab + lane;
        #pragma unroll
        for (int k = 0; k < 8; ++k) ec[k] = p[k << 6];
    }

    for (int s = 0; s < NSTEP; ++s) {
        // prefetch odd coeffs for this step (consumed after even layer)
        const float4* ob = otab + s * 512;
        float4 oc0 = ob[(7 << 6) + lanem1];
        float4 oc[8];
        #pragma unroll
        for (int k = 0; k < 8; ++k) oc[k] = ob[(k << 6) + lane];

        // ---- even layer, boundary pairs first (k=0, k=7) so the 4 boundary
        // shuffles can issue early and hide their latency under k=1..6
        #pragma unroll
        for (int t = 0; t < 2; ++t) {
            int k = t ? 7 : 0;
            float c = ec[k].x, sn = ec[k].y, sp = ec[k].z, cp = ec[k].w;
            #pragma unroll
            for (int r = 0; r < 2; ++r) {
                float ar = xr[r][2*k],   ai = xi[r][2*k];
                float br = xr[r][2*k+1], bi = xi[r][2*k+1];
                float tr = c*ar - sn*br;
                float ti = c*ai - sn*bi;
                xr[r][2*k]   = sp*tr - cp*ti;
                xi[r][2*k]   = sp*ti + cp*tr;
                xr[r][2*k+1] = c*br + sn*ar;
                xi[r][2*k+1] = c*bi + sn*ai;
            }
        }

        // boundary shuffles on post-even values
        float xnr[2], xni[2], xlr[2], xli[2];
        #pragma unroll
        for (int r = 0; r < 2; ++r) {
            xnr[r] = __shfl_down(xr[r][0], 1, 64);   // right neighbor's col0
            xni[r] = __shfl_down(xi[r][0], 1, 64);
            xlr[r] = __shfl_up(xr[r][15], 1, 64);    // left neighbor's col15
            xli[r] = __shfl_up(xi[r][15], 1, 64);
        }

        // remaining even pairs k=1..6
        #pragma unroll
        for (int k = 1; k < 7; ++k) {
            float c = ec[k].x, sn = ec[k].y, sp = ec[k].z, cp = ec[k].w;
            #pragma unroll
            for (int r = 0; r < 2; ++r) {
                float ar = xr[r][2*k],   ai = xi[r][2*k];
                float br = xr[r][2*k+1], bi = xi[r][2*k+1];
                float tr = c*ar - sn*br;
                float ti = c*ai - sn*bi;
                xr[r][2*k]   = sp*tr - cp*ti;
                xi[r][2*k]   = sp*ti + cp*tr;
                xr[r][2*k+1] = c*br + sn*ar;
                xi[r][2*k+1] = c*bi + sn*ai;
            }
        }

        // prefetch next step's even coeffs (consumed next iteration)
        if (s + 1 < NSTEP) {
            const float4* p = etab + (s + 1) * 512 + lane;
            #pragma unroll
            for (int k = 0; k < 8; ++k) ec[k] = p[k << 6];
        }

        // ---- odd layer: internal pairs oc[k-1] -> local cols (2k-1, 2k)
        #pragma unroll
        for (int k = 1; k < 8; ++k) {
            float c = oc[k-1].x, sn = oc[k-1].y, sp = oc[k-1].z, cp = oc[k-1].w;
            #pragma unroll
            for (int r = 0; r < 2; ++r) {
                float ar = xr[r][2*k-1], ai = xi[r][2*k-1];
                float br = xr[r][2*k],   bi = xi[r][2*k];
                float tr = c*ar - sn*br;
                float ti = c*ai - sn*bi;
                xr[r][2*k-1] = sp*tr - cp*ti;
                xi[r][2*k-1] = sp*ti + cp*tr;
                xr[r][2*k]   = c*br + sn*ar;
                xi[r][2*k]   = c*bi + sn*ai;
            }
        }
        // right boundary pair (our col15 = "a", neighbor col0 = "b"): update col15
        {
            float c = oc[7].x, sn = oc[7].y, sp = oc[7].z, cp = oc[7].w;
            #pragma unroll
            for (int r = 0; r < 2; ++r) {
                float ar = xr[r][15], ai = xi[r][15];
                float tr = c*ar - sn*xnr[r];
                float ti = c*ai - sn*xni[r];
                xr[r][15] = sp*tr - cp*ti;
                xi[r][15] = sp*ti + cp*tr;
            }
        }
        // left boundary pair (left col15 = "a", our col0 = "b"): update col0
        {
            float c = oc0.x, sn = oc0.y;
            #pragma unroll
            for (int r = 0; r < 2; ++r) {
                float br = xr[r][0], bi = xi[r][0];
                xr[r][0] = c*br + sn*xlr[r];
                xi[r][0] = c*bi + sn*xli[r];
            }
        }
    }

    // --- omega phase + store (coalesced) ---
    float4 wc[8];
    #pragma unroll
    for (int q = 0; q < 8; ++q) wc[q] = wtab[(q << 6) + lane];  // (cw0,sw0,cw1,sw1) cols 2q,2q+1

    #pragma unroll
    for (int r = 0; r < 2; ++r) {
        float4* pre = reinterpret_cast<float4*>(out + (row0 + r) * HDIM + colbase);
        float4* pim = reinterpret_cast<float4*>(out + BDIM * HDIM + (row0 + r) * HDIM + colbase);
        #pragma unroll
        for (int h = 0; h < 4; ++h) {
            float4 wa = wc[2*h];
            float4 wb = wc[2*h + 1];
            float4 vr, vi;
            vr.x = xr[r][4*h]   * wa.x - xi[r][4*h]   * wa.y;
            vi.x = xr[r][4*h]   * wa.y + xi[r][4*h]   * wa.x;
            vr.y = xr[r][4*h+1] * wa.z - xi[r][4*h+1] * wa.w;
            vi.y = xr[r][4*h+1] * wa.w + xi[r][4*h+1] * wa.z;
            vr.z = xr[r][4*h+2] * wb.x - xi[r][4*h+2] * wb.y;
            vi.z = xr[r][4*h+2] * wb.y + xi[r][4*h+2] * wb.x;
            vr.w = xr[r][4*h+3] * wb.z - xi[r][4*h+3] * wb.w;
            vi.w = xr[r][4*h+3] * wb.w + xi[r][4*h+3] * wb.z;
            pre[h] = vr;
            pim[h] = vi;
        }
    }
}

extern "C" void kernel_launch(void* const* d_in, const int* in_sizes, int n_in,
                              void* d_out, int out_size, void* d_ws, size_t ws_size,
                              hipStream_t stream)
{
    const float* x_re  = (const float*)d_in[0];
    const float* x_im  = (const float*)d_in[1];
    const float* omega = (const float*)d_in[2];
    const float* eth   = (const float*)d_in[3];
    const float* oth   = (const float*)d_in[4];
    const float* eph   = (const float*)d_in[5];
    const float* oph   = (const float*)d_in[6];

    char* ws = (char*)d_ws;
    float4* etab = (float4*)ws;                             // 512 KB
    float4* otab = (float4*)(ws + NSTEP * 512 * 16);        // 512 KB
    float2* wtab = (float2*)(ws + 2 * NSTEP * 512 * 16);    // 8 KB

    coeff_kernel<<<260, 256, 0, stream>>>(omega, eth, oth, eph, oph, etab, otab, wtab);
    eunn_kernel<<<BDIM / 8, 256, 0, stream>>>(x_re, x_im, etab, otab,
                                              (const float4*)wtab, (float*)d_out);
}